// Round 3
// baseline (49.591 us; speedup 1.0000x reference)
//
#include <hip/hip_runtime.h>

// x[n_experts=8][n_task=8][batch=1024][dim=512] fp32 -> out[t][b][e][d], rows
// orthonormalized per (t,b) sample via Cholesky-QR (== classical Gram-Schmidt
// in exact arithmetic): G = X X^T, L = chol(G), Q = L^{-1} X.
// One wave per sample; 8x512 matrix in registers (8 floats/lane/vector).
// All 36 Gram dot-reductions batched into ONE butterfly round (full ILP)
// instead of GS's 8 serial reduce->update rounds.

#define NE 8
#define DIM 512
#define NSAMP 8192  // n_task * batch

typedef float f32x4 __attribute__((ext_vector_type(4)));  // native vec for nontemporal builtins

__global__ __launch_bounds__(256) void gs_chol_kernel(const float* __restrict__ x,
                                                      float* __restrict__ out) {
    const int lane = threadIdx.x & 63;
    const int w = blockIdx.x * 4 + (threadIdx.x >> 6);  // sample id
    const int t = w >> 10;
    const int b = w & 1023;

    // Load 8 vectors, elements d = c*256 + lane*4 + k (coalesced float4)
    float v[NE][8];
#pragma unroll
    for (int e = 0; e < NE; ++e) {
        const float* src = x + ((size_t)(e * 8 + t) * 1024 + b) * DIM;
#pragma unroll
        for (int c = 0; c < 2; ++c) {
            f32x4 f = *reinterpret_cast<const f32x4*>(src + c * 256 + lane * 4);
#pragma unroll
            for (int k = 0; k < 4; ++k) v[e][c * 4 + k] = f[k];
        }
    }

    // Lower-triangle Gram matrix: 36 per-lane partial dots
    float g[36];
#pragma unroll
    for (int i = 0; i < NE; ++i) {
#pragma unroll
        for (int j = 0; j <= i; ++j) {
            float p = 0.f;
#pragma unroll
            for (int k = 0; k < 8; ++k) p = fmaf(v[i][k], v[j][k], p);
            g[i * (i + 1) / 2 + j] = p;
        }
    }
    // One batched butterfly round: 36 independent reductions, full ILP
#pragma unroll
    for (int off = 32; off > 0; off >>= 1) {
#pragma unroll
        for (int m = 0; m < 36; ++m) g[m] += __shfl_xor(g[m], off, 64);
    }

    // In-place Cholesky of g (packed lower, row-major), redundant per lane.
    float invd[NE];
#pragma unroll
    for (int i = 0; i < NE; ++i) {
#pragma unroll
        for (int j = 0; j <= i; ++j) {
            float s = g[i * (i + 1) / 2 + j];
#pragma unroll
            for (int k = 0; k < NE; ++k) {
                if (k < j) s = fmaf(-g[i * (i + 1) / 2 + k], g[j * (j + 1) / 2 + k], s);
            }
            if (j == i) {
                invd[i] = 1.0f / sqrtf(s);
            } else {
                g[i * (i + 1) / 2 + j] = s * invd[j];
            }
        }
    }

    // Forward substitution in place: Q_i = (v_i - sum_{j<i} L[i][j] Q_j) * invd[i]
#pragma unroll
    for (int i = 0; i < NE; ++i) {
#pragma unroll
        for (int k = 0; k < 8; ++k) {
            float acc = v[i][k];
#pragma unroll
            for (int j = 0; j < NE; ++j) {
                if (j < i) acc = fmaf(-g[i * (i + 1) / 2 + j], v[j][k], acc);
            }
            v[i][k] = acc * invd[i];
        }
    }

    // Non-temporal stores: output never re-read; don't evict input from L3.
#pragma unroll
    for (int e = 0; e < NE; ++e) {
        float* dst = out + ((size_t)w * NE + e) * DIM;
#pragma unroll
        for (int c = 0; c < 2; ++c) {
            f32x4 f;
#pragma unroll
            for (int k = 0; k < 4; ++k) f[k] = v[e][c * 4 + k];
            __builtin_nontemporal_store(f, reinterpret_cast<f32x4*>(dst + c * 256 + lane * 4));
        }
    }
}

extern "C" void kernel_launch(void* const* d_in, const int* in_sizes, int n_in,
                              void* d_out, int out_size, void* d_ws, size_t ws_size,
                              hipStream_t stream) {
    const float* x = (const float*)d_in[0];
    float* out = (float*)d_out;
    gs_chol_kernel<<<NSAMP / 4, 256, 0, stream>>>(x, out);
}

// Round 4
// 44.354 us; speedup vs baseline: 1.1181x; 1.1181x over previous
//
#include <hip/hip_runtime.h>

// x[n_experts=8][n_task=8][batch=1024][dim=512] fp32 -> out[t][b][e][d]:
// per-(t,b) classical Gram-Schmidt over the 8 expert rows.
// One wave per sample; 8x512 matrix in registers (8 floats/lane/vector).
// Round-1 GS structure (VGPR 48, best measured) + rsqrt + NT stores.

#define NE 8
#define DIM 512
#define NSAMP 8192  // n_task * batch

typedef float f32x4 __attribute__((ext_vector_type(4)));

__device__ __forceinline__ float wave_sum(float p) {
#pragma unroll
    for (int off = 32; off > 0; off >>= 1)
        p += __shfl_xor(p, off, 64);
    return p;
}

__global__ __launch_bounds__(256) void gs_kernel(const float* __restrict__ x,
                                                 float* __restrict__ out) {
    const int lane = threadIdx.x & 63;
    const int w = blockIdx.x * 4 + (threadIdx.x >> 6);  // sample id
    const int t = w >> 10;
    const int b = w & 1023;

    // Load 8 vectors: d = c*256 + lane*4 + k (two coalesced float4 loads each)
    float v[NE][8];
#pragma unroll
    for (int e = 0; e < NE; ++e) {
        const float* src = x + ((size_t)(e * 8 + t) * 1024 + b) * DIM;
#pragma unroll
        for (int c = 0; c < 2; ++c) {
            f32x4 f = *reinterpret_cast<const f32x4*>(src + c * 256 + lane * 4);
#pragma unroll
            for (int k = 0; k < 4; ++k) v[e][c * 4 + k] = f[k];
        }
    }

    // Classical Gram-Schmidt, matching the reference exactly.
#pragma unroll
    for (int i = 0; i < NE; ++i) {
        float coef[NE];
#pragma unroll
        for (int j = 0; j < NE; ++j) {
            if (j < i) {
                float p = 0.f;
#pragma unroll
                for (int k = 0; k < 8; ++k) p = fmaf(v[j][k], v[i][k], p);
                coef[j] = wave_sum(p);
            }
        }
#pragma unroll
        for (int k = 0; k < 8; ++k) {
            float acc = 0.f;
#pragma unroll
            for (int j = 0; j < NE; ++j) {
                if (j < i) acc = fmaf(coef[j], v[j][k], acc);
            }
            v[i][k] -= acc;
        }
        float p = 0.f;
#pragma unroll
        for (int k = 0; k < 8; ++k) p = fmaf(v[i][k], v[i][k], p);
        float inv = rsqrtf(wave_sum(p));  // v_rsq_f32: shorter critical path than sqrt+div
#pragma unroll
        for (int k = 0; k < 8; ++k) v[i][k] *= inv;
    }

    // Non-temporal stores: output never re-read by this kernel.
#pragma unroll
    for (int e = 0; e < NE; ++e) {
        float* dst = out + ((size_t)w * NE + e) * DIM;
#pragma unroll
        for (int c = 0; c < 2; ++c) {
            f32x4 f;
#pragma unroll
            for (int k = 0; k < 4; ++k) f[k] = v[e][c * 4 + k];
            __builtin_nontemporal_store(f, reinterpret_cast<f32x4*>(dst + c * 256 + lane * 4));
        }
    }
}

extern "C" void kernel_launch(void* const* d_in, const int* in_sizes, int n_in,
                              void* d_out, int out_size, void* d_ws, size_t ws_size,
                              hipStream_t stream) {
    const float* x = (const float*)d_in[0];
    float* out = (float*)d_out;
    gs_kernel<<<NSAMP / 4, 256, 0, stream>>>(x, out);
}

// Round 5
// 43.880 us; speedup vs baseline: 1.1302x; 1.0108x over previous
//
#include <hip/hip_runtime.h>

// x[n_experts=8][n_task=8][batch=1024][dim=512] fp32 -> out[t][b][e][d]:
// per-(t,b) classical Gram-Schmidt over the 8 expert rows.
// One wave per sample; 8x512 matrix in registers (8 floats/lane/vector).
// Wave reductions via DPP (row_shr + row_bcast) -> pure VALU, zero LDS-pipe
// ops (round-4 used 216 ds_swizzle/wave; LDS pipe was a stacked bottleneck).

#define NE 8
#define DIM 512
#define NSAMP 8192  // n_task * batch

typedef float f32x4 __attribute__((ext_vector_type(4)));

template <int CTRL>
__device__ __forceinline__ float dpp_add(float x) {
    int t = __builtin_amdgcn_update_dpp(0, __float_as_int(x), CTRL, 0xf, 0xf, true);
    return x + __int_as_float(t);
}

// Full-wave sum; result returned as a wave-uniform (SGPR) value.
__device__ __forceinline__ float wave_sum(float p) {
    p = dpp_add<0x111>(p);  // row_shr:1
    p = dpp_add<0x112>(p);  // row_shr:2
    p = dpp_add<0x114>(p);  // row_shr:4
    p = dpp_add<0x118>(p);  // row_shr:8   -> lane 15/31/47/63 hold row sums
    p = dpp_add<0x142>(p);  // row_bcast:15 -> lane 31 = rows0+1, lane 63 = rows2+3
    p = dpp_add<0x143>(p);  // row_bcast:31 -> lane 63 = total
    return __int_as_float(__builtin_amdgcn_readlane(__float_as_int(p), 63));
}

__global__ __launch_bounds__(256) void gs_kernel(const float* __restrict__ x,
                                                 float* __restrict__ out) {
    const int lane = threadIdx.x & 63;
    const int w = blockIdx.x * 4 + (threadIdx.x >> 6);  // sample id
    const int t = w >> 10;
    const int b = w & 1023;

    // Load 8 vectors: d = c*256 + lane*4 + k (two coalesced float4 loads each)
    float v[NE][8];
#pragma unroll
    for (int e = 0; e < NE; ++e) {
        const float* src = x + ((size_t)(e * 8 + t) * 1024 + b) * DIM;
#pragma unroll
        for (int c = 0; c < 2; ++c) {
            f32x4 f = *reinterpret_cast<const f32x4*>(src + c * 256 + lane * 4);
#pragma unroll
            for (int k = 0; k < 4; ++k) v[e][c * 4 + k] = f[k];
        }
    }

    // Classical Gram-Schmidt, matching the reference exactly.
#pragma unroll
    for (int i = 0; i < NE; ++i) {
        float coef[NE];  // wave-uniform -> SGPRs
#pragma unroll
        for (int j = 0; j < NE; ++j) {
            if (j < i) {
                float p = 0.f;
#pragma unroll
                for (int k = 0; k < 8; ++k) p = fmaf(v[j][k], v[i][k], p);
                coef[j] = wave_sum(p);
            }
        }
#pragma unroll
        for (int k = 0; k < 8; ++k) {
            float acc = 0.f;
#pragma unroll
            for (int j = 0; j < NE; ++j) {
                if (j < i) acc = fmaf(coef[j], v[j][k], acc);
            }
            v[i][k] -= acc;
        }
        float p = 0.f;
#pragma unroll
        for (int k = 0; k < 8; ++k) p = fmaf(v[i][k], v[i][k], p);
        float inv = rsqrtf(wave_sum(p));  // v_rsq_f32 on uniform value
#pragma unroll
        for (int k = 0; k < 8; ++k) v[i][k] *= inv;
    }

    // Non-temporal stores: output never re-read by this kernel.
#pragma unroll
    for (int e = 0; e < NE; ++e) {
        float* dst = out + ((size_t)w * NE + e) * DIM;
#pragma unroll
        for (int c = 0; c < 2; ++c) {
            f32x4 f;
#pragma unroll
            for (int k = 0; k < 4; ++k) f[k] = v[e][c * 4 + k];
            __builtin_nontemporal_store(f, reinterpret_cast<f32x4*>(dst + c * 256 + lane * 4));
        }
    }
}

extern "C" void kernel_launch(void* const* d_in, const int* in_sizes, int n_in,
                              void* d_out, int out_size, void* d_ws, size_t ws_size,
                              hipStream_t stream) {
    const float* x = (const float*)d_in[0];
    float* out = (float*)d_out;
    gs_kernel<<<NSAMP / 4, 256, 0, stream>>>(x, out);
}